// Round 1
// baseline (578.083 us; speedup 1.0000x reference)
//
#include <hip/hip_runtime.h>
#include <math.h>

#define K_BINS   65536
#define B_IMG    32
#define CHUNKS   16                      // scan chunks per image (4096 bins each)
#define BLOCKS_PER_IMG 256
#define NBLOCKS  (B_IMG * BLOCKS_PER_IMG) // 8192
#define EPS_F    1e-7f

// ws layout
static const size_t HIST_BYTES = (size_t)B_IMG * K_BINS * 4;   // 8 MiB
static const size_t OFF_FOCAL  = HIST_BYTES;                   // double[NBLOCKS]
static const size_t OFF_NUM    = OFF_FOCAL + (size_t)NBLOCKS * 8;
static const size_t OFF_DEN    = OFF_NUM   + (size_t)NBLOCKS * 8; // uint[NBLOCKS]
static const size_t OFF_CTOT   = OFF_DEN   + (size_t)NBLOCKS * 4; // uint[B_IMG*CHUNKS]

// ---------------- pass 1: focal sum + positive-margin histogram + denom ----
__global__ __launch_bounds__(256)
void k_pass1(const float* __restrict__ X, const float* __restrict__ T,
             unsigned* __restrict__ hist, double* __restrict__ fpart,
             unsigned* __restrict__ dpart) {
    const int blk = blockIdx.x, tid = threadIdx.x;
    const int img = blk >> 8;
    const size_t base = ((size_t)img << 20) + ((size_t)(blk & 255) << 12);
    const float4* X4 = (const float4*)(X + base);
    const float4* T4 = (const float4*)(T + base);
    unsigned* h = hist + ((size_t)img << 16);

    float fsum = 0.f;
    int   dcnt = 0;
    for (int r = 0; r < 4; ++r) {
        float4 xv = X4[(r << 8) + tid];
        float4 tv = T4[(r << 8) + tid];
#pragma unroll
        for (int j = 0; j < 4; ++j) {
            float x = (&xv.x)[j];
            float t = (&tv.x)[j];
            float e   = __expf(-fabsf(x));
            float inv = 1.f / (1.f + e);
            float p   = (x >= 0.f) ? inv : e * inv;
            p = fminf(fmaxf(p, EPS_F), 1.f - EPS_F);
            float bce = fmaxf(x, 0.f) - x * t + __logf(1.f + e);
            float pt  = (t == 1.f) ? p : 1.f - p;
            float om  = 1.f - pt;
            fsum += om * om * bce;
            if (t == 1.f) {
                float m = 2.f * p - 1.f;
                int bin = (int)((m * 0.5f + 0.5f) * (float)K_BINS);
                bin = bin < 0 ? 0 : (bin > K_BINS - 1 ? K_BINS - 1 : bin);
                atomicAdd(&h[bin], 1u);
                dcnt++;
            }
        }
    }
    // block reduce (wave64 shuffle + LDS)
    double fd = (double)fsum;
    for (int o = 32; o > 0; o >>= 1) {
        fd   += __shfl_down(fd, o, 64);
        dcnt += __shfl_down(dcnt, o, 64);
    }
    __shared__ double sF[4];
    __shared__ int    sD[4];
    int lane = tid & 63, wid = tid >> 6;
    if (lane == 0) { sF[wid] = fd; sD[wid] = dcnt; }
    __syncthreads();
    if (tid == 0) {
        fpart[blk] = sF[0] + sF[1] + sF[2] + sF[3];
        dpart[blk] = (unsigned)(sD[0] + sD[1] + sD[2] + sD[3]);
    }
}

// ---------------- scan A: per-chunk totals ---------------------------------
__global__ __launch_bounds__(256)
void k_scanA(const unsigned* __restrict__ hist, unsigned* __restrict__ ctot) {
    const int blk = blockIdx.x;          // B_IMG*CHUNKS
    const int img = blk >> 4, c = blk & 15;
    const uint4* h4 = (const uint4*)(hist + ((size_t)img << 16) + ((size_t)c << 12));
    const int tid = threadIdx.x;
    unsigned s = 0;
    for (int r = 0; r < 4; ++r) {
        uint4 v = h4[(r << 8) + tid];
        s += v.x + v.y + v.z + v.w;
    }
    for (int o = 32; o > 0; o >>= 1) s += __shfl_down(s, o, 64);
    __shared__ unsigned sW[4];
    if ((tid & 63) == 0) sW[tid >> 6] = s;
    __syncthreads();
    if (tid == 0) ctot[blk] = sW[0] + sW[1] + sW[2] + sW[3];
}

// ---------------- scan B: in-place suffix-exclusive sums -------------------
__global__ __launch_bounds__(256)
void k_scanB(unsigned* __restrict__ hist, const unsigned* __restrict__ ctot) {
    const int blk = blockIdx.x;
    const int img = blk >> 4, c = blk & 15;
    unsigned* h = hist + ((size_t)img << 16) + ((size_t)c << 12);
    const int tid = threadIdx.x;

    unsigned running = 0;
    for (int cc = c + 1; cc < CHUNKS; ++cc) running += ctot[(img << 4) + cc];

    unsigned v[16];
    uint4 a0 = *(const uint4*)&h[tid * 16 + 0];
    uint4 a1 = *(const uint4*)&h[tid * 16 + 4];
    uint4 a2 = *(const uint4*)&h[tid * 16 + 8];
    uint4 a3 = *(const uint4*)&h[tid * 16 + 12];
    v[0]=a0.x; v[1]=a0.y; v[2]=a0.z; v[3]=a0.w;
    v[4]=a1.x; v[5]=a1.y; v[6]=a1.z; v[7]=a1.w;
    v[8]=a2.x; v[9]=a2.y; v[10]=a2.z; v[11]=a2.w;
    v[12]=a3.x; v[13]=a3.y; v[14]=a3.z; v[15]=a3.w;
    unsigned tsum = 0;
#pragma unroll
    for (int i = 0; i < 16; ++i) tsum += v[i];

    // suffix-inclusive scan across 256 threads (Hillis-Steele, ping-pong)
    __shared__ unsigned sc[2][256];
    sc[0][tid] = tsum;
    __syncthreads();
    int pi = 0;
    for (int off = 1; off < 256; off <<= 1) {
        unsigned val = sc[pi][tid];
        if (tid + off < 256) val += sc[pi][tid + off];
        sc[pi ^ 1][tid] = val;
        __syncthreads();
        pi ^= 1;
    }
    unsigned sufT = sc[pi][tid] - tsum;  // sum over threads > tid

    unsigned acc = 0, out[16];
#pragma unroll
    for (int i = 15; i >= 0; --i) { out[i] = running + sufT + acc; acc += v[i]; }
    *(uint4*)&h[tid * 16 + 0]  = make_uint4(out[0], out[1], out[2], out[3]);
    *(uint4*)&h[tid * 16 + 4]  = make_uint4(out[4], out[5], out[6], out[7]);
    *(uint4*)&h[tid * 16 + 8]  = make_uint4(out[8], out[9], out[10], out[11]);
    *(uint4*)&h[tid * 16 + 12] = make_uint4(out[12], out[13], out[14], out[15]);
}

// ---------------- pass 3: num = sum |m| * (S_excl[bin] + [t==1]) -----------
__global__ __launch_bounds__(256)
void k_pass3(const float* __restrict__ X, const float* __restrict__ T,
             const unsigned* __restrict__ suf, double* __restrict__ npart) {
    const int blk = blockIdx.x, tid = threadIdx.x;
    const int img = blk >> 8;
    const size_t base = ((size_t)img << 20) + ((size_t)(blk & 255) << 12);
    const float4* X4 = (const float4*)(X + base);
    const float4* T4 = (const float4*)(T + base);
    const unsigned* S = suf + ((size_t)img << 16);

    double nsum = 0.0;
    for (int r = 0; r < 4; ++r) {
        float4 xv = X4[(r << 8) + tid];
        float4 tv = T4[(r << 8) + tid];
#pragma unroll
        for (int j = 0; j < 4; ++j) {
            float x = (&xv.x)[j];
            float t = (&tv.x)[j];
            float e   = __expf(-fabsf(x));
            float inv = 1.f / (1.f + e);
            float p   = (x >= 0.f) ? inv : e * inv;
            p = fminf(fmaxf(p, EPS_F), 1.f - EPS_F);
            float m = (t == 1.f) ? (2.f * p - 1.f) : (1.f - 2.f * p);
            int bin = (int)((m * 0.5f + 0.5f) * (float)K_BINS);
            bin = bin < 0 ? 0 : (bin > K_BINS - 1 ? K_BINS - 1 : bin);
            unsigned cnt = S[bin] + (t == 1.f ? 1u : 0u);
            nsum += (double)fabsf(m) * (double)cnt;
        }
    }
    for (int o = 32; o > 0; o >>= 1) nsum += __shfl_down(nsum, o, 64);
    __shared__ double sN[4];
    if ((tid & 63) == 0) sN[tid >> 6] = nsum;
    __syncthreads();
    if (tid == 0) npart[blk] = sN[0] + sN[1] + sN[2] + sN[3];
}

// ---------------- final combine --------------------------------------------
__global__ __launch_bounds__(256)
void k_final(const double* __restrict__ fpart, const double* __restrict__ npart,
             const unsigned* __restrict__ dpart, float* __restrict__ out) {
    const int tid = threadIdx.x;
    __shared__ double sF[256];
    double f = 0.0;
    for (int i = tid; i < NBLOCKS; i += 256) f += fpart[i];
    sF[tid] = f;
    __syncthreads();
    for (int s2 = 128; s2 > 0; s2 >>= 1) {
        if (tid < s2) sF[tid] += sF[tid + s2];
        __syncthreads();
    }
    __shared__ double sL[32];
    if (tid < 32) {
        double num = 0.0;
        unsigned long long den = 0;
        for (int c = 0; c < BLOCKS_PER_IMG; ++c) {
            num += npart[tid * BLOCKS_PER_IMG + c];
            den += dpart[tid * BLOCKS_PER_IMG + c];
        }
        sL[tid] = (den == 0ull) ? 0.0 : num / (double)den;
    }
    __syncthreads();
    if (tid == 0) {
        double lsum = 0.0;
        for (int i = 0; i < B_IMG; ++i) lsum += sL[i];
        double lmean = lsum / (double)B_IMG;
        double fmean = sF[0] / (double)((size_t)B_IMG << 20);
        out[0] = (float)(fabs(0.5 * fmean) + fabs(0.5 * lmean));
    }
}

extern "C" void kernel_launch(void* const* d_in, const int* in_sizes, int n_in,
                              void* d_out, int out_size, void* d_ws, size_t ws_size,
                              hipStream_t stream) {
    const float* X = (const float*)d_in[0];
    const float* T = (const float*)d_in[1];
    unsigned char* ws = (unsigned char*)d_ws;
    unsigned* hist = (unsigned*)ws;
    double*   fpart = (double*)(ws + OFF_FOCAL);
    double*   npart = (double*)(ws + OFF_NUM);
    unsigned* dpart = (unsigned*)(ws + OFF_DEN);
    unsigned* ctot  = (unsigned*)(ws + OFF_CTOT);

    hipMemsetAsync(hist, 0, HIST_BYTES, stream);
    k_pass1<<<NBLOCKS, 256, 0, stream>>>(X, T, hist, fpart, dpart);
    k_scanA<<<B_IMG * CHUNKS, 256, 0, stream>>>(hist, ctot);
    k_scanB<<<B_IMG * CHUNKS, 256, 0, stream>>>(hist, ctot);
    k_pass3<<<NBLOCKS, 256, 0, stream>>>(X, T, hist, npart);
    k_final<<<1, 256, 0, stream>>>(fpart, npart, dpart, (float*)d_out);
}

// Round 2
// 200.983 us; speedup vs baseline: 2.8763x; 2.8763x over previous
//
#include <hip/hip_runtime.h>
#include <math.h>

#define KB_   4096
#define B_IMG 32
#define EPS_F 1e-7f

// ---------------- pass 1: fused focal + per-block LDS histograms -----------
// Per block: count hist (positives) + weight hist (|m| of ALL elements),
// focal partial, selfW partial (sum |m| over positives), denom partial.
__global__ __launch_bounds__(256)
void k_pass1(const float* __restrict__ X, const float* __restrict__ T,
             unsigned* __restrict__ gcnt, float* __restrict__ gwt,
             double* __restrict__ fpart, double* __restrict__ swpart,
             unsigned* __restrict__ dpart, int iters) {
    const int blk = blockIdx.x, tid = threadIdx.x;
    __shared__ __align__(16) unsigned hc[KB_];
    __shared__ __align__(16) float    hw[KB_];
    for (int i = tid; i < KB_; i += 256) { hc[i] = 0u; hw[i] = 0.f; }
    __syncthreads();

    const size_t base4 = (size_t)blk * (size_t)iters * 256;   // float4 index
    const float4* X4 = (const float4*)X + base4;
    const float4* T4 = (const float4*)T + base4;

    float fsum = 0.f, swsum = 0.f;
    unsigned dcnt = 0;
    for (int r = 0; r < iters; ++r) {
        float4 xv = X4[r * 256 + tid];
        float4 tv = T4[r * 256 + tid];
#pragma unroll
        for (int j = 0; j < 4; ++j) {
            float x = (&xv.x)[j];
            float t = (&tv.x)[j];
            float e   = __expf(-fabsf(x));
            float inv = 1.f / (1.f + e);
            float p   = (x >= 0.f) ? inv : e * inv;
            p = fminf(fmaxf(p, EPS_F), 1.f - EPS_F);
            float bce = fmaxf(x, 0.f) - x * t + __logf(1.f + e);
            float pt  = (t == 1.f) ? p : 1.f - p;
            float om  = 1.f - pt;
            fsum += om * om * bce;
            float m  = (t == 1.f) ? (2.f * p - 1.f) : (1.f - 2.f * p);
            float am = fabsf(m);
            int bin = (int)((m * 0.5f + 0.5f) * (float)KB_);
            bin = bin < 0 ? 0 : (bin > KB_ - 1 ? KB_ - 1 : bin);
            atomicAdd(&hw[bin], am);
            if (t == 1.f) { atomicAdd(&hc[bin], 1u); dcnt++; swsum += am; }
        }
    }
    __syncthreads();

    // flush per-block hists (plain coalesced stores, NO atomics)
    unsigned* gc = gcnt + (size_t)blk * KB_;
    float*    gw = gwt  + (size_t)blk * KB_;
    for (int i = tid; i < KB_; i += 256) { gc[i] = hc[i]; gw[i] = hw[i]; }

    // block reduce of scalars (reuse hw LDS space for cross-wave staging)
    double fd = (double)fsum, sd = (double)swsum;
    unsigned dc = dcnt;
    for (int o = 32; o > 0; o >>= 1) {
        fd += __shfl_down(fd, o, 64);
        sd += __shfl_down(sd, o, 64);
        dc += __shfl_down(dc, o, 64);
    }
    __syncthreads();
    double* dsh = (double*)hw;   // 16KB region, realigned use after flush
    int lane = tid & 63, wid = tid >> 6;
    if (lane == 0) { dsh[wid] = fd; dsh[8 + wid] = sd; hc[wid] = dc; }
    __syncthreads();
    if (tid == 0) {
        fpart[blk]  = dsh[0] + dsh[1] + dsh[2] + dsh[3];
        swpart[blk] = dsh[8] + dsh[9] + dsh[10] + dsh[11];
        dpart[blk]  = hc[0] + hc[1] + hc[2] + hc[3];
    }
}

// ---------------- reduce per-block hists -> per-image hists ----------------
__global__ __launch_bounds__(256)
void k_reduce(const unsigned* __restrict__ gcnt, const float* __restrict__ gwt,
              unsigned* __restrict__ icnt, float* __restrict__ iwt, int bpi) {
    const int img = blockIdx.x >> 3, chunk = blockIdx.x & 7, tid = threadIdx.x;
    const int b0 = chunk * 512 + tid * 2;
    unsigned c0 = 0, c1 = 0; float w0 = 0.f, w1 = 0.f;
    for (int j = 0; j < bpi; ++j) {
        size_t base = (size_t)(img * bpi + j) * KB_ + b0;
        uint2  c = *(const uint2*)(gcnt + base);
        float2 w = *(const float2*)(gwt + base);
        c0 += c.x; c1 += c.y; w0 += w.x; w1 += w.y;
    }
    size_t ob = (size_t)img * KB_ + b0;
    *(uint2*)(icnt + ob)  = make_uint2(c0, c1);
    *(float2*)(iwt + ob)  = make_float2(w0, w1);
}

// ---------------- per-image: suffix scan + dot -> loss ---------------------
__global__ __launch_bounds__(256)
void k_scan(const unsigned* __restrict__ icnt, const float* __restrict__ iwt,
            const double* __restrict__ swpart, const unsigned* __restrict__ dpart,
            double* __restrict__ loss, int bpi) {
    const int img = blockIdx.x, tid = threadIdx.x;
    const unsigned* c = icnt + (size_t)img * KB_;
    const float*    w = iwt  + (size_t)img * KB_;

    unsigned v[16]; float wv[16];
    uint4 a0 = *(const uint4*)&c[tid * 16 + 0];
    uint4 a1 = *(const uint4*)&c[tid * 16 + 4];
    uint4 a2 = *(const uint4*)&c[tid * 16 + 8];
    uint4 a3 = *(const uint4*)&c[tid * 16 + 12];
    v[0]=a0.x; v[1]=a0.y; v[2]=a0.z; v[3]=a0.w;
    v[4]=a1.x; v[5]=a1.y; v[6]=a1.z; v[7]=a1.w;
    v[8]=a2.x; v[9]=a2.y; v[10]=a2.z; v[11]=a2.w;
    v[12]=a3.x; v[13]=a3.y; v[14]=a3.z; v[15]=a3.w;
    float4 b0 = *(const float4*)&w[tid * 16 + 0];
    float4 b1 = *(const float4*)&w[tid * 16 + 4];
    float4 b2 = *(const float4*)&w[tid * 16 + 8];
    float4 b3 = *(const float4*)&w[tid * 16 + 12];
    wv[0]=b0.x; wv[1]=b0.y; wv[2]=b0.z; wv[3]=b0.w;
    wv[4]=b1.x; wv[5]=b1.y; wv[6]=b1.z; wv[7]=b1.w;
    wv[8]=b2.x; wv[9]=b2.y; wv[10]=b2.z; wv[11]=b2.w;
    wv[12]=b3.x; wv[13]=b3.y; wv[14]=b3.z; wv[15]=b3.w;

    unsigned tsum = 0;
#pragma unroll
    for (int i = 0; i < 16; ++i) tsum += v[i];

    // suffix-inclusive scan over thread totals (Hillis-Steele ping-pong)
    __shared__ unsigned sc[2][256];
    sc[0][tid] = tsum;
    __syncthreads();
    int pi = 0;
    for (int off = 1; off < 256; off <<= 1) {
        unsigned val = sc[pi][tid];
        if (tid + off < 256) val += sc[pi][tid + off];
        sc[pi ^ 1][tid] = val;
        __syncthreads();
        pi ^= 1;
    }
    unsigned sufT = sc[pi][tid] - tsum;   // counts in threads > tid

    double nsum = 0.0; unsigned acc = 0;
#pragma unroll
    for (int i = 15; i >= 0; --i) {
        unsigned S = sufT + acc;          // positives strictly above bin i
        nsum += (double)wv[i] * (double)S;
        acc += v[i];
    }

    for (int o = 32; o > 0; o >>= 1) nsum += __shfl_down(nsum, o, 64);
    __shared__ double sN[4];
    __shared__ double sSW;
    __shared__ unsigned long long sDEN;
    if ((tid & 63) == 0) sN[tid >> 6] = nsum;
    if (tid < 64) {
        double swv = (tid < bpi) ? swpart[img * bpi + tid] : 0.0;
        unsigned long long dv = (tid < bpi) ? (unsigned long long)dpart[img * bpi + tid] : 0ull;
        for (int o = 32; o > 0; o >>= 1) {
            swv += __shfl_down(swv, o, 64);
            dv  += __shfl_down(dv, o, 64);
        }
        if (tid == 0) { sSW = swv; sDEN = dv; }
    }
    __syncthreads();
    if (tid == 0) {
        double num = sN[0] + sN[1] + sN[2] + sN[3] + sSW;
        loss[img] = (sDEN == 0ull) ? 0.0 : num / fmax((double)sDEN, 1.0);
    }
}

// ---------------- final combine --------------------------------------------
__global__ __launch_bounds__(256)
void k_final(const double* __restrict__ fpart, int nb,
             const double* __restrict__ loss, float* __restrict__ out) {
    const int tid = threadIdx.x;
    double f = 0.0;
    for (int i = tid; i < nb; i += 256) f += fpart[i];
    __shared__ double sF[256];
    sF[tid] = f;
    __syncthreads();
    for (int s = 128; s > 0; s >>= 1) {
        if (tid < s) sF[tid] += sF[tid + s];
        __syncthreads();
    }
    if (tid == 0) {
        double l = 0.0;
        for (int i = 0; i < B_IMG; ++i) l += loss[i];
        double lmean = l / (double)B_IMG;
        double fmean = sF[0] / 33554432.0;   // 32 * 2^20
        out[0] = (float)(fabs(0.5 * fmean) + fabs(0.5 * lmean));
    }
}

extern "C" void kernel_launch(void* const* d_in, const int* in_sizes, int n_in,
                              void* d_out, int out_size, void* d_ws, size_t ws_size,
                              hipStream_t stream) {
    const float* X = (const float*)d_in[0];
    const float* T = (const float*)d_in[1];

    // choose block count by available workspace (deterministic per run)
    int NB = 1024;
    for (;;) {
        size_t need = (size_t)NB * KB_ * 8            // gcnt + gwt
                    + (size_t)B_IMG * KB_ * 8         // icnt + iwt
                    + (size_t)NB * 20                 // fpart + swpart + dpart
                    + 256 + 1024;                     // loss + slack
        if (need <= ws_size || NB <= 256) break;
        NB >>= 1;
    }
    const int bpi   = NB / B_IMG;                     // blocks per image
    const int iters = (1 << 25) / NB / 1024;          // per-thread float4 iters

    unsigned char* ws = (unsigned char*)d_ws;
    unsigned* gcnt  = (unsigned*)ws;
    float*    gwt   = (float*)(ws + (size_t)NB * KB_ * 4);
    unsigned* icnt  = (unsigned*)(ws + (size_t)NB * KB_ * 8);
    float*    iwt   = (float*)(ws + (size_t)NB * KB_ * 8 + (size_t)B_IMG * KB_ * 4);
    unsigned char* tail = ws + (size_t)NB * KB_ * 8 + (size_t)B_IMG * KB_ * 8;
    double*   fpart = (double*)tail;
    double*   swpart= (double*)(tail + (size_t)NB * 8);
    unsigned* dpart = (unsigned*)(tail + (size_t)NB * 16);
    double*   loss  = (double*)(tail + (size_t)NB * 20 + 32);

    k_pass1 <<<NB, 256, 0, stream>>>(X, T, gcnt, gwt, fpart, swpart, dpart, iters);
    k_reduce<<<B_IMG * 8, 256, 0, stream>>>(gcnt, gwt, icnt, iwt, bpi);
    k_scan  <<<B_IMG, 256, 0, stream>>>(icnt, iwt, swpart, dpart, loss, bpi);
    k_final <<<1, 256, 0, stream>>>(fpart, NB, loss, (float*)d_out);
}

// Round 3
// 80.481 us; speedup vs baseline: 7.1828x; 2.4973x over previous
//
#include <hip/hip_runtime.h>
#include <math.h>

#define KB_   2048
#define B_IMG 32
#define EPS_F 1e-7f
#define WSCALE 1048576.0f          // 2^20 fixed-point for |m|
#define WINV   (1.0f / 1048576.0f)
#define CNT_SHIFT 42

// ---------------- pass 1: fused focal + packed-u64 LDS histogram -----------
__global__ __launch_bounds__(256)
void k_pass1(const float* __restrict__ X, const float* __restrict__ T,
             unsigned* __restrict__ gcnt, float* __restrict__ gwt,
             double* __restrict__ fpart, double* __restrict__ swpart, int iters) {
    const int blk = blockIdx.x, tid = threadIdx.x;
    __shared__ __align__(16) unsigned long long h8[KB_];   // 16 KB
    for (int i = tid; i < KB_; i += 256) h8[i] = 0ull;
    __syncthreads();

    const size_t base4 = (size_t)blk * (size_t)iters * 256;
    const float4* X4 = (const float4*)X + base4;
    const float4* T4 = (const float4*)T + base4;

    float fsum = 0.f, swsum = 0.f;
    for (int r = 0; r < iters; ++r) {
        float4 xv = X4[r * 256 + tid];
        float4 tv = T4[r * 256 + tid];
#pragma unroll
        for (int j = 0; j < 4; ++j) {
            float x = (&xv.x)[j];
            float t = (&tv.x)[j];
            // pt = sigmoid(x) if t==1 else sigmoid(-x); shared e = exp(-|x|)
            float e   = __expf(-fabsf(x));
            float inv = 1.f / (1.f + e);
            float lo  = e * inv;                   // sigmoid(-|x|)
            bool  zpos = ((x >= 0.f) == (t == 1.f));
            float ptr_ = zpos ? inv : lo;          // raw pt
            float pt   = fminf(fmaxf(ptr_, EPS_F), 1.f - EPS_F);
            float bce  = -__logf(ptr_);            // == bce-with-logits here
            float om   = 1.f - pt;
            fsum += om * om * bce;
            float m  = __builtin_fmaf(2.f, pt, -1.f);   // margin, both classes
            float am = fabsf(m);
            swsum += (t == 1.f) ? am : 0.f;
            int bin = (int)__builtin_fmaf(m, (float)(KB_ / 2), (float)(KB_ / 2));
            bin = bin < 0 ? 0 : (bin > KB_ - 1 ? KB_ - 1 : bin);
            unsigned long long incr =
                ((unsigned long long)(t == 1.f ? 1u : 0u) << CNT_SHIFT)
                | (unsigned long long)__float2uint_rn(am * WSCALE);
            atomicAdd(&h8[bin], incr);
        }
    }
    __syncthreads();

    // flush per-block hist (plain coalesced stores)
    unsigned* gc = gcnt + (size_t)blk * KB_;
    float*    gw = gwt  + (size_t)blk * KB_;
    for (int i = tid; i < KB_; i += 256) {
        unsigned long long v = h8[i];
        gc[i] = (unsigned)(v >> CNT_SHIFT);
        gw[i] = (float)(v & ((1ull << CNT_SHIFT) - 1ull)) * WINV;
    }

    // block reduce of scalars
    double fd = (double)fsum, sd = (double)swsum;
    for (int o = 32; o > 0; o >>= 1) {
        fd += __shfl_down(fd, o, 64);
        sd += __shfl_down(sd, o, 64);
    }
    __syncthreads();
    double* dsh = (double*)h8;
    int lane = tid & 63, wid = tid >> 6;
    if (lane == 0) { dsh[wid] = fd; dsh[8 + wid] = sd; }
    __syncthreads();
    if (tid == 0) {
        fpart[blk]  = dsh[0] + dsh[1] + dsh[2] + dsh[3];
        swpart[blk] = dsh[8] + dsh[9] + dsh[10] + dsh[11];
    }
}

// ---------------- reduce per-block hists -> per-image hists ----------------
__global__ __launch_bounds__(256)
void k_reduce(const unsigned* __restrict__ gcnt, const float* __restrict__ gwt,
              unsigned* __restrict__ icnt, float* __restrict__ iwt, int bpi) {
    const int img = blockIdx.x >> 2, chunk = blockIdx.x & 3, tid = threadIdx.x;
    const int b0 = chunk * 512 + tid * 2;
    unsigned c0 = 0, c1 = 0; float w0 = 0.f, w1 = 0.f;
    for (int j = 0; j < bpi; ++j) {
        size_t base = (size_t)(img * bpi + j) * KB_ + b0;
        uint2  c = *(const uint2*)(gcnt + base);
        float2 w = *(const float2*)(gwt + base);
        c0 += c.x; c1 += c.y; w0 += w.x; w1 += w.y;
    }
    size_t ob = (size_t)img * KB_ + b0;
    *(uint2*)(icnt + ob) = make_uint2(c0, c1);
    *(float2*)(iwt + ob) = make_float2(w0, w1);
}

// ---------------- per-image: suffix scan + dot -> loss ---------------------
__global__ __launch_bounds__(256)
void k_scan(const unsigned* __restrict__ icnt, const float* __restrict__ iwt,
            const double* __restrict__ swpart, double* __restrict__ loss, int bpi) {
    const int img = blockIdx.x, tid = threadIdx.x;
    const unsigned* c = icnt + (size_t)img * KB_;
    const float*    w = iwt  + (size_t)img * KB_;

    unsigned v[8]; float wv[8];
    uint4 a0 = *(const uint4*)&c[tid * 8 + 0];
    uint4 a1 = *(const uint4*)&c[tid * 8 + 4];
    v[0]=a0.x; v[1]=a0.y; v[2]=a0.z; v[3]=a0.w;
    v[4]=a1.x; v[5]=a1.y; v[6]=a1.z; v[7]=a1.w;
    float4 b0 = *(const float4*)&w[tid * 8 + 0];
    float4 b1 = *(const float4*)&w[tid * 8 + 4];
    wv[0]=b0.x; wv[1]=b0.y; wv[2]=b0.z; wv[3]=b0.w;
    wv[4]=b1.x; wv[5]=b1.y; wv[6]=b1.z; wv[7]=b1.w;

    unsigned tsum = 0;
#pragma unroll
    for (int i = 0; i < 8; ++i) tsum += v[i];

    __shared__ unsigned sc[2][256];
    sc[0][tid] = tsum;
    __syncthreads();
    int pi = 0;
    for (int off = 1; off < 256; off <<= 1) {
        unsigned val = sc[pi][tid];
        if (tid + off < 256) val += sc[pi][tid + off];
        sc[pi ^ 1][tid] = val;
        __syncthreads();
        pi ^= 1;
    }
    unsigned sufT = sc[pi][tid] - tsum;     // positives in threads > tid
    unsigned denom = sc[pi][0];             // total positives in image

    double nsum = 0.0; unsigned acc = 0;
#pragma unroll
    for (int i = 7; i >= 0; --i) {
        nsum += (double)wv[i] * (double)(sufT + acc);
        acc += v[i];
    }

    for (int o = 32; o > 0; o >>= 1) nsum += __shfl_down(nsum, o, 64);
    __shared__ double sN[4];
    __shared__ double sSW;
    if ((tid & 63) == 0) sN[tid >> 6] = nsum;
    if (tid < 64) {
        double swv = (tid < bpi) ? swpart[img * bpi + tid] : 0.0;
        for (int o = 32; o > 0; o >>= 1) swv += __shfl_down(swv, o, 64);
        if (tid == 0) sSW = swv;
    }
    __syncthreads();
    if (tid == 0) {
        double num = sN[0] + sN[1] + sN[2] + sN[3] + sSW;
        loss[img] = (denom == 0u) ? 0.0 : num / fmax((double)denom, 1.0);
    }
}

// ---------------- final combine --------------------------------------------
__global__ __launch_bounds__(256)
void k_final(const double* __restrict__ fpart, int nb,
             const double* __restrict__ loss, float* __restrict__ out) {
    const int tid = threadIdx.x;
    double f = 0.0;
    for (int i = tid; i < nb; i += 256) f += fpart[i];
    __shared__ double sF[256];
    sF[tid] = f;
    __syncthreads();
    for (int s = 128; s > 0; s >>= 1) {
        if (tid < s) sF[tid] += sF[tid + s];
        __syncthreads();
    }
    if (tid == 0) {
        double l = 0.0;
        for (int i = 0; i < B_IMG; ++i) l += loss[i];
        double lmean = l / (double)B_IMG;
        double fmean = sF[0] / 33554432.0;
        out[0] = (float)(fabs(0.5 * fmean) + fabs(0.5 * lmean));
    }
}

extern "C" void kernel_launch(void* const* d_in, const int* in_sizes, int n_in,
                              void* d_out, int out_size, void* d_ws, size_t ws_size,
                              hipStream_t stream) {
    const float* X = (const float*)d_in[0];
    const float* T = (const float*)d_in[1];

    int NB = 2048;
    for (;;) {
        size_t need = (size_t)NB * KB_ * 8            // gcnt + gwt
                    + (size_t)B_IMG * KB_ * 8         // icnt + iwt
                    + (size_t)NB * 16                 // fpart + swpart
                    + 256 + 1024;
        if (need <= ws_size || NB <= 256) break;
        NB >>= 1;
    }
    const int bpi   = NB / B_IMG;
    const int iters = (1 << 25) / (NB * 1024);

    unsigned char* ws = (unsigned char*)d_ws;
    unsigned* gcnt = (unsigned*)ws;
    float*    gwt  = (float*)(ws + (size_t)NB * KB_ * 4);
    unsigned* icnt = (unsigned*)(ws + (size_t)NB * KB_ * 8);
    float*    iwt  = (float*)(ws + (size_t)NB * KB_ * 8 + (size_t)B_IMG * KB_ * 4);
    unsigned char* tail = ws + (size_t)NB * KB_ * 8 + (size_t)B_IMG * KB_ * 8;
    double*   fpart  = (double*)tail;
    double*   swpart = (double*)(tail + (size_t)NB * 8);
    double*   loss   = (double*)(tail + (size_t)NB * 16 + 32);

    k_pass1 <<<NB, 256, 0, stream>>>(X, T, gcnt, gwt, fpart, swpart, iters);
    k_reduce<<<B_IMG * 4, 256, 0, stream>>>(gcnt, gwt, icnt, iwt, bpi);
    k_scan  <<<B_IMG, 256, 0, stream>>>(icnt, iwt, swpart, loss, bpi);
    k_final <<<1, 256, 0, stream>>>(fpart, NB, loss, (float*)d_out);
}

// Round 4
// 79.408 us; speedup vs baseline: 7.2799x; 1.0135x over previous
//
#include <hip/hip_runtime.h>
#include <math.h>

#define KB_   1024
#define B_IMG 32
#define WSCALE 1048576.0f          // 2^20 fixed-point for |m|
#define WINV   (1.0f / 1048576.0f)
#define CNT_SHIFT 42
#define LN2F 0.6931471805599453f

// ---------------- pass 1: fused focal + packed-u64 LDS histogram -----------
__global__ __launch_bounds__(256)
void k_pass1(const float* __restrict__ X, const float* __restrict__ T,
             unsigned* __restrict__ gcnt, float* __restrict__ gwt,
             double* __restrict__ fpart, double* __restrict__ swpart, int iters) {
    const int blk = blockIdx.x, tid = threadIdx.x;
    __shared__ __align__(16) unsigned long long h8[KB_];   // 8 KB
    for (int i = tid; i < KB_; i += 256) h8[i] = 0ull;
    __syncthreads();

    const size_t base4 = (size_t)blk * (size_t)iters * 256;
    const float4* Xp = (const float4*)X + base4 + tid;
    const float4* Tp = (const float4*)T + base4 + tid;

    float fsum = 0.f, swsum = 0.f;

    auto process = [&](float4 xv, float4 tv) {
#pragma unroll
        for (int j = 0; j < 4; ++j) {
            float x = (&xv.x)[j];
            float t = (&tv.x)[j];
            float s   = __builtin_fmaf(2.f, t, -1.f);   // +1 / -1
            float z   = x * s;                          // signed logit
            float az  = fabsf(z);
            float e   = __expf(-az);                    // exp(-|z|)
            float o   = 1.f + e;
            float inv = 1.f / o;                        // 1/(1+e)
            float am  = __builtin_fmaf(-e, inv, inv);   // (1-e)/(1+e) = |margin|
            float sm  = copysignf(am, z);               // signed margin
            float om  = __builtin_fmaf(-0.5f, sm, 0.5f);// 1 - pt  (= sigmoid(-z))
            float bce = __builtin_fmaf(__logf(o), 1.0f, fmaxf(-z, 0.f)); // log(1+e)+relu(-z)
            fsum  = __builtin_fmaf(om * om, bce, fsum);
            swsum = __builtin_fmaf(am, t, swsum);       // t is exactly 0/1
            float binf = __builtin_fmaf(sm, (float)(KB_ / 2), (float)(KB_ / 2));
            int bin = ((int)binf) & (KB_ - 1);          // safe: binf in [0, KB_)
            unsigned wfix = __float2uint_rn(am * WSCALE);
            unsigned cnt  = (unsigned)t;
            unsigned long long incr =
                ((unsigned long long)cnt << CNT_SHIFT) | (unsigned long long)wfix;
            atomicAdd(&h8[bin], incr);
        }
    };

    // 2-deep software pipeline (iters >= 2 always)
    float4 xa = Xp[0],   ta = Tp[0];
    float4 xb = Xp[256], tb = Tp[256];
    for (int r = 2; r < iters; ++r) {
        float4 xn = Xp[r * 256], tn = Tp[r * 256];
        process(xa, ta);
        xa = xb; ta = tb; xb = xn; tb = tn;
    }
    process(xa, ta);
    process(xb, tb);
    __syncthreads();

    // flush per-block hist (plain coalesced stores)
    unsigned* gc = gcnt + (size_t)blk * KB_;
    float*    gw = gwt  + (size_t)blk * KB_;
    for (int i = tid; i < KB_; i += 256) {
        unsigned long long v = h8[i];
        gc[i] = (unsigned)(v >> CNT_SHIFT);
        gw[i] = (float)(v & ((1ull << CNT_SHIFT) - 1ull)) * WINV;
    }

    // block reduce of scalars
    double fd = (double)fsum, sd = (double)swsum;
    for (int o = 32; o > 0; o >>= 1) {
        fd += __shfl_down(fd, o, 64);
        sd += __shfl_down(sd, o, 64);
    }
    __syncthreads();
    double* dsh = (double*)h8;
    int lane = tid & 63, wid = tid >> 6;
    if (lane == 0) { dsh[wid] = fd; dsh[8 + wid] = sd; }
    __syncthreads();
    if (tid == 0) {
        fpart[blk]  = dsh[0] + dsh[1] + dsh[2] + dsh[3];
        swpart[blk] = dsh[8] + dsh[9] + dsh[10] + dsh[11];
    }
}

// ---------------- reduce per-block hists -> per-image hists ----------------
__global__ __launch_bounds__(256)
void k_reduce(const unsigned* __restrict__ gcnt, const float* __restrict__ gwt,
              unsigned* __restrict__ icnt, float* __restrict__ iwt, int bpi) {
    const int img = blockIdx.x >> 1, chunk = blockIdx.x & 1, tid = threadIdx.x;
    const int b0 = chunk * 512 + tid * 2;
    unsigned c0 = 0, c1 = 0; float w0 = 0.f, w1 = 0.f;
    for (int j = 0; j < bpi; ++j) {
        size_t base = (size_t)(img * bpi + j) * KB_ + b0;
        uint2  c = *(const uint2*)(gcnt + base);
        float2 w = *(const float2*)(gwt + base);
        c0 += c.x; c1 += c.y; w0 += w.x; w1 += w.y;
    }
    size_t ob = (size_t)img * KB_ + b0;
    *(uint2*)(icnt + ob) = make_uint2(c0, c1);
    *(float2*)(iwt + ob) = make_float2(w0, w1);
}

// ---------------- per-image: suffix scan + dot -> loss ---------------------
__global__ __launch_bounds__(256)
void k_scan(const unsigned* __restrict__ icnt, const float* __restrict__ iwt,
            const double* __restrict__ swpart, double* __restrict__ loss, int bpi) {
    const int img = blockIdx.x, tid = threadIdx.x;
    const unsigned* c = icnt + (size_t)img * KB_;
    const float*    w = iwt  + (size_t)img * KB_;

    uint4  a0 = *(const uint4*)&c[tid * 4];
    float4 b0 = *(const float4*)&w[tid * 4];
    unsigned v[4]  = {a0.x, a0.y, a0.z, a0.w};
    float    wv[4] = {b0.x, b0.y, b0.z, b0.w};

    unsigned tsum = v[0] + v[1] + v[2] + v[3];

    __shared__ unsigned sc[2][256];
    sc[0][tid] = tsum;
    __syncthreads();
    int pi = 0;
    for (int off = 1; off < 256; off <<= 1) {
        unsigned val = sc[pi][tid];
        if (tid + off < 256) val += sc[pi][tid + off];
        sc[pi ^ 1][tid] = val;
        __syncthreads();
        pi ^= 1;
    }
    unsigned sufT  = sc[pi][tid] - tsum;    // positives in threads > tid
    unsigned denom = sc[pi][0];             // total positives in image

    double nsum = 0.0; unsigned acc = 0;
#pragma unroll
    for (int i = 3; i >= 0; --i) {
        nsum += (double)wv[i] * (double)(sufT + acc);
        acc += v[i];
    }

    for (int o = 32; o > 0; o >>= 1) nsum += __shfl_down(nsum, o, 64);
    __shared__ double sN[4];
    __shared__ double sSW;
    if ((tid & 63) == 0) sN[tid >> 6] = nsum;
    if (tid < 64) {
        double swv = (tid < bpi) ? swpart[img * bpi + tid] : 0.0;
        for (int o = 32; o > 0; o >>= 1) swv += __shfl_down(swv, o, 64);
        if (tid == 0) sSW = swv;
    }
    __syncthreads();
    if (tid == 0) {
        double num = sN[0] + sN[1] + sN[2] + sN[3] + sSW;
        loss[img] = (denom == 0u) ? 0.0 : num / fmax((double)denom, 1.0);
    }
}

// ---------------- final combine --------------------------------------------
__global__ __launch_bounds__(256)
void k_final(const double* __restrict__ fpart, int nb,
             const double* __restrict__ loss, float* __restrict__ out) {
    const int tid = threadIdx.x;
    double f = 0.0;
    for (int i = tid; i < nb; i += 256) f += fpart[i];
    __shared__ double sF[256];
    sF[tid] = f;
    __syncthreads();
    for (int s = 128; s > 0; s >>= 1) {
        if (tid < s) sF[tid] += sF[tid + s];
        __syncthreads();
    }
    if (tid == 0) {
        double l = 0.0;
        for (int i = 0; i < B_IMG; ++i) l += loss[i];
        double lmean = l / (double)B_IMG;
        double fmean = sF[0] / 33554432.0;
        out[0] = (float)(fabs(0.5 * fmean) + fabs(0.5 * lmean));
    }
}

extern "C" void kernel_launch(void* const* d_in, const int* in_sizes, int n_in,
                              void* d_out, int out_size, void* d_ws, size_t ws_size,
                              hipStream_t stream) {
    const float* X = (const float*)d_in[0];
    const float* T = (const float*)d_in[1];

    int NB = 2048;
    for (;;) {
        size_t need = (size_t)NB * KB_ * 8            // gcnt + gwt
                    + (size_t)B_IMG * KB_ * 8         // icnt + iwt
                    + (size_t)NB * 16                 // fpart + swpart
                    + 256 + 1024;
        if (need <= ws_size || NB <= 256) break;
        NB >>= 1;
    }
    const int bpi   = NB / B_IMG;
    const int iters = (1 << 25) / (NB * 1024);

    unsigned char* ws = (unsigned char*)d_ws;
    unsigned* gcnt = (unsigned*)ws;
    float*    gwt  = (float*)(ws + (size_t)NB * KB_ * 4);
    unsigned* icnt = (unsigned*)(ws + (size_t)NB * KB_ * 8);
    float*    iwt  = (float*)(ws + (size_t)NB * KB_ * 8 + (size_t)B_IMG * KB_ * 4);
    unsigned char* tail = ws + (size_t)NB * KB_ * 8 + (size_t)B_IMG * KB_ * 8;
    double*   fpart  = (double*)tail;
    double*   swpart = (double*)(tail + (size_t)NB * 8);
    double*   loss   = (double*)(tail + (size_t)NB * 16 + 32);

    k_pass1 <<<NB, 256, 0, stream>>>(X, T, gcnt, gwt, fpart, swpart, iters);
    k_reduce<<<B_IMG * 2, 256, 0, stream>>>(gcnt, gwt, icnt, iwt, bpi);
    k_scan  <<<B_IMG, 256, 0, stream>>>(icnt, iwt, swpart, loss, bpi);
    k_final <<<1, 256, 0, stream>>>(fpart, NB, loss, (float*)d_out);
}

// Round 5
// 59.135 us; speedup vs baseline: 9.7756x; 1.3428x over previous
//
#include <hip/hip_runtime.h>
#include <math.h>

#define KB_   1024                 // z-bins over [-8, 8], Dz = 1/64
#define B_IMG 32

// ---------------- pass 1: z-binned packed count histogram ------------------
// Per element: z = t? x : -x ; bin = clamp(z*64+512) ; h[bin] += (t<<16)|1.
__global__ __launch_bounds__(256)
void k_pass1(const float* __restrict__ X, const float* __restrict__ T,
             unsigned* __restrict__ ghist, int iters) {
    const int blk = blockIdx.x, tid = threadIdx.x;
    __shared__ __align__(16) unsigned h[KB_];      // 4 KB
    for (int i = tid; i < KB_; i += 256) h[i] = 0u;
    __syncthreads();

    const size_t base4 = (size_t)blk * (size_t)iters * 256;
    const float4* Xp = (const float4*)X + base4 + tid;
    const float4* Tp = (const float4*)T + base4 + tid;

    auto process = [&](float4 xv, float4 tv) {
#pragma unroll
        for (int j = 0; j < 4; ++j) {
            float x = (&xv.x)[j];
            float t = (&tv.x)[j];
            float s    = __builtin_fmaf(2.f, t, -1.f);          // +1 / -1
            float z    = x * s;                                  // signed logit
            float binf = __builtin_fmaf(z, 64.f, 512.f);
            binf = fminf(fmaxf(binf, 0.f), 1023.f);
            int bin = (int)binf;
            unsigned incr = (unsigned)__builtin_fmaf(t, 65536.f, 1.f); // (t<<16)|1
            atomicAdd(&h[bin], incr);
        }
    };

    // 2-deep software pipeline (iters >= 2)
    float4 xa = Xp[0],   ta = Tp[0];
    float4 xb = Xp[256], tb = Tp[256];
    for (int r = 2; r < iters; ++r) {
        float4 xn = Xp[r * 256], tn = Tp[r * 256];
        process(xa, ta);
        xa = xb; ta = tb; xb = xn; tb = tn;
    }
    process(xa, ta);
    process(xb, tb);
    __syncthreads();

    unsigned* g = ghist + (size_t)blk * KB_;
    for (int i = tid; i < KB_; i += 256) g[i] = h[i];
}

// ---------------- per-image: accumulate + suffix scan + analytic dot -------
// num = sum_k am_k * [ ctot_k * Sab_k + p_k*(ctot_k+1)/2 ]   (exact pos-rank
// sum + expectation-corrected pos/neg interleave); focal = sum_k ctot_k*f_k.
__global__ __launch_bounds__(256)
void k_scan(const unsigned* __restrict__ ghist, double* __restrict__ loss,
            double* __restrict__ fpart, int bpi) {
    const int img = blockIdx.x, tid = threadIdx.x;
    const unsigned* g = ghist + (size_t)img * (size_t)bpi * KB_;

    uint4 acc = make_uint4(0u, 0u, 0u, 0u);
    for (int j = 0; j < bpi; ++j) {
        uint4 v = *(const uint4*)&g[(size_t)j * KB_ + tid * 4];
        acc.x += v.x; acc.y += v.y; acc.z += v.z; acc.w += v.w;
    }
    unsigned pk[4], ck[4];
    pk[0] = acc.x >> 16; ck[0] = acc.x & 0xffffu;
    pk[1] = acc.y >> 16; ck[1] = acc.y & 0xffffu;
    pk[2] = acc.z >> 16; ck[2] = acc.z & 0xffffu;
    pk[3] = acc.w >> 16; ck[3] = acc.w & 0xffffu;

    unsigned tsum = pk[0] + pk[1] + pk[2] + pk[3];

    // suffix-inclusive scan of positive counts over threads (bins ascend in z)
    __shared__ unsigned sc[2][256];
    sc[0][tid] = tsum;
    __syncthreads();
    int pi = 0;
    for (int off = 1; off < 256; off <<= 1) {
        unsigned val = sc[pi][tid];
        if (tid + off < 256) val += sc[pi][tid + off];
        sc[pi ^ 1][tid] = val;
        __syncthreads();
        pi ^= 1;
    }
    unsigned sufT  = sc[pi][tid] - tsum;   // positives in threads > tid
    unsigned denom = sc[pi][0];            // total positives in image

    double nsum = 0.0, fsum = 0.0;
    unsigned a2 = 0;
#pragma unroll
    for (int i = 3; i >= 0; --i) {
        int b = tid * 4 + i;
        double zc = ((double)b + 0.5 - 512.0) * (1.0 / 64.0);
        double az = fabs(zc);
        double e  = exp(-az);
        double am = (1.0 - e) / (1.0 + e);                       // |margin|
        double om = (zc >= 0.0) ? e / (1.0 + e) : 1.0 / (1.0 + e); // sigmoid(-z)
        double bce = ((zc < 0.0) ? -zc : 0.0) + log1p(e);         // softplus(-z)
        double fk = om * om * bce;
        double Sab = (double)(sufT + a2);                        // pos strictly above
        double c = (double)ck[i], p = (double)pk[i];
        nsum += am * (c * Sab + 0.5 * p * (c + 1.0));
        fsum += fk * c;
        a2 += pk[i];
    }

    for (int o = 32; o > 0; o >>= 1) {
        nsum += __shfl_down(nsum, o, 64);
        fsum += __shfl_down(fsum, o, 64);
    }
    __shared__ double sN[4], sFo[4];
    if ((tid & 63) == 0) { sN[tid >> 6] = nsum; sFo[tid >> 6] = fsum; }
    __syncthreads();
    if (tid == 0) {
        double num = sN[0] + sN[1] + sN[2] + sN[3];
        loss[img]  = (denom == 0u) ? 0.0 : num / fmax((double)denom, 1.0);
        fpart[img] = sFo[0] + sFo[1] + sFo[2] + sFo[3];
    }
}

// ---------------- final combine --------------------------------------------
__global__ __launch_bounds__(64)
void k_final(const double* __restrict__ loss, const double* __restrict__ fpart,
             float* __restrict__ out) {
    const int tid = threadIdx.x;
    double l = (tid < B_IMG) ? loss[tid] : 0.0;
    double f = (tid < B_IMG) ? fpart[tid] : 0.0;
    for (int o = 32; o > 0; o >>= 1) {
        l += __shfl_down(l, o, 64);
        f += __shfl_down(f, o, 64);
    }
    if (tid == 0) {
        double lmean = l / (double)B_IMG;
        double fmean = f / 33554432.0;            // 32 * 2^20 elements
        out[0] = (float)(fabs(0.5 * fmean) + fabs(0.5 * lmean));
    }
}

extern "C" void kernel_launch(void* const* d_in, const int* in_sizes, int n_in,
                              void* d_out, int out_size, void* d_ws, size_t ws_size,
                              hipStream_t stream) {
    const float* X = (const float*)d_in[0];
    const float* T = (const float*)d_in[1];

    int NB = 2048;                                 // 8 blocks/CU, 4 KB LDS each
    for (;;) {
        size_t need = (size_t)NB * KB_ * 4 + 1024;
        if (need <= ws_size || NB <= 256) break;
        NB >>= 1;
    }
    const int bpi   = NB / B_IMG;
    const int iters = (1 << 25) / (NB * 1024);     // float4 iters per thread

    unsigned char* ws = (unsigned char*)d_ws;
    unsigned* ghist = (unsigned*)ws;
    double*   loss  = (double*)(ws + (size_t)NB * KB_ * 4);
    double*   fpart = loss + B_IMG;

    k_pass1<<<NB, 256, 0, stream>>>(X, T, ghist, iters);
    k_scan <<<B_IMG, 256, 0, stream>>>(ghist, loss, fpart, bpi);
    k_final<<<1, 64, 0, stream>>>(loss, fpart, (float*)d_out);
}

// Round 6
// 58.897 us; speedup vs baseline: 9.8152x; 1.0041x over previous
//
#include <hip/hip_runtime.h>
#include <math.h>

#define KB_   1024                 // z-bins over [-8, 8], Dz = 1/64
#define B_IMG 32

// ---------------- pass 1: z-binned packed count histogram ------------------
// Per element: z = t? x : -x ; bin = clamp(z*64+512) ; h[bin] += (t<<16)|1.
// 4-deep software pipeline: 8 x 16B loads in flight per lane.
template <int ITERS>
__global__ __launch_bounds__(256)
void k_pass1(const float* __restrict__ X, const float* __restrict__ T,
             unsigned* __restrict__ ghist) {
    const int blk = blockIdx.x, tid = threadIdx.x;
    __shared__ __align__(16) unsigned h[KB_];      // 4 KB
    for (int i = tid; i < KB_; i += 256) h[i] = 0u;
    __syncthreads();

    const size_t base4 = (size_t)blk * (size_t)ITERS * 256;
    const float4* Xp = (const float4*)X + base4 + tid;
    const float4* Tp = (const float4*)T + base4 + tid;

    auto process = [&](float4 xv, float4 tv) {
#pragma unroll
        for (int j = 0; j < 4; ++j) {
            float x = (&xv.x)[j];
            float t = (&tv.x)[j];
            float s    = __builtin_fmaf(2.f, t, -1.f);           // +1 / -1
            float z    = x * s;                                   // signed logit
            float binf = __builtin_fmaf(z, 64.f, 512.f);
            binf = fminf(fmaxf(binf, 0.f), 1023.f);
            int bin = (int)binf;
            unsigned incr = (unsigned)__builtin_fmaf(t, 65536.f, 1.f); // (t<<16)|1
            atomicAdd(&h[bin], incr);
        }
    };

    float4 bx[4], bt[4];
#pragma unroll
    for (int r = 0; r < 4; ++r) { bx[r] = Xp[r * 256]; bt[r] = Tp[r * 256]; }
#pragma unroll
    for (int r = 0; r < ITERS; ++r) {
        float4 xv = bx[r & 3], tv = bt[r & 3];
        if (r + 4 < ITERS) {
            bx[r & 3] = Xp[(r + 4) * 256];
            bt[r & 3] = Tp[(r + 4) * 256];
        }
        process(xv, tv);
    }
    __syncthreads();

    unsigned* g = ghist + (size_t)blk * KB_;
    for (int i = tid; i < KB_; i += 256) g[i] = h[i];
}

// ---------------- per-image: accumulate + suffix scan + analytic dot -------
__global__ __launch_bounds__(256)
void k_scan(const unsigned* __restrict__ ghist, double* __restrict__ loss,
            double* __restrict__ fpart, int bpi) {
    const int img = blockIdx.x, tid = threadIdx.x;
    const unsigned* g = ghist + (size_t)img * (size_t)bpi * KB_;

    uint4 acc = make_uint4(0u, 0u, 0u, 0u);
    for (int j = 0; j < bpi; ++j) {
        uint4 v = *(const uint4*)&g[(size_t)j * KB_ + tid * 4];
        acc.x += v.x; acc.y += v.y; acc.z += v.z; acc.w += v.w;
    }
    unsigned pk[4], ck[4];
    pk[0] = acc.x >> 16; ck[0] = acc.x & 0xffffu;
    pk[1] = acc.y >> 16; ck[1] = acc.y & 0xffffu;
    pk[2] = acc.z >> 16; ck[2] = acc.z & 0xffffu;
    pk[3] = acc.w >> 16; ck[3] = acc.w & 0xffffu;

    unsigned tsum = pk[0] + pk[1] + pk[2] + pk[3];

    __shared__ unsigned sc[2][256];
    sc[0][tid] = tsum;
    __syncthreads();
    int pi = 0;
    for (int off = 1; off < 256; off <<= 1) {
        unsigned val = sc[pi][tid];
        if (tid + off < 256) val += sc[pi][tid + off];
        sc[pi ^ 1][tid] = val;
        __syncthreads();
        pi ^= 1;
    }
    unsigned sufT  = sc[pi][tid] - tsum;   // positives in threads > tid
    unsigned denom = sc[pi][0];            // total positives in image

    double nsum = 0.0, fsum = 0.0;
    unsigned a2 = 0;
#pragma unroll
    for (int i = 3; i >= 0; --i) {
        int b = tid * 4 + i;
        double zc = ((double)b + 0.5 - 512.0) * (1.0 / 64.0);
        double az = fabs(zc);
        double e  = exp(-az);
        double am = (1.0 - e) / (1.0 + e);                         // |margin|
        double om = (zc >= 0.0) ? e / (1.0 + e) : 1.0 / (1.0 + e); // sigmoid(-z)
        double bce = ((zc < 0.0) ? -zc : 0.0) + log1p(e);          // softplus(-z)
        double fk = om * om * bce;
        double Sab = (double)(sufT + a2);                          // pos strictly above
        double c = (double)ck[i], p = (double)pk[i];
        nsum += am * (c * Sab + 0.5 * p * (c + 1.0));
        fsum += fk * c;
        a2 += pk[i];
    }

    for (int o = 32; o > 0; o >>= 1) {
        nsum += __shfl_down(nsum, o, 64);
        fsum += __shfl_down(fsum, o, 64);
    }
    __shared__ double sN[4], sFo[4];
    if ((tid & 63) == 0) { sN[tid >> 6] = nsum; sFo[tid >> 6] = fsum; }
    __syncthreads();
    if (tid == 0) {
        double num = sN[0] + sN[1] + sN[2] + sN[3];
        loss[img]  = (denom == 0u) ? 0.0 : num / fmax((double)denom, 1.0);
        fpart[img] = sFo[0] + sFo[1] + sFo[2] + sFo[3];
    }
}

// ---------------- final combine --------------------------------------------
__global__ __launch_bounds__(64)
void k_final(const double* __restrict__ loss, const double* __restrict__ fpart,
             float* __restrict__ out) {
    const int tid = threadIdx.x;
    double l = (tid < B_IMG) ? loss[tid] : 0.0;
    double f = (tid < B_IMG) ? fpart[tid] : 0.0;
    for (int o = 32; o > 0; o >>= 1) {
        l += __shfl_down(l, o, 64);
        f += __shfl_down(f, o, 64);
    }
    if (tid == 0) {
        double lmean = l / (double)B_IMG;
        double fmean = f / 33554432.0;            // 32 * 2^20 elements
        out[0] = (float)(fabs(0.5 * fmean) + fabs(0.5 * lmean));
    }
}

extern "C" void kernel_launch(void* const* d_in, const int* in_sizes, int n_in,
                              void* d_out, int out_size, void* d_ws, size_t ws_size,
                              hipStream_t stream) {
    const float* X = (const float*)d_in[0];
    const float* T = (const float*)d_in[1];

    int NB = 2048;                                 // 8 blocks/CU, 4 KB LDS each
    for (;;) {
        size_t need = (size_t)NB * KB_ * 4 + 1024;
        if (need <= ws_size || NB <= 256) break;
        NB >>= 1;
    }
    const int bpi = NB / B_IMG;

    unsigned char* ws = (unsigned char*)d_ws;
    unsigned* ghist = (unsigned*)ws;
    double*   loss  = (double*)(ws + (size_t)NB * KB_ * 4);
    double*   fpart = loss + B_IMG;

    switch (NB) {
        case 2048: k_pass1<16> <<<2048, 256, 0, stream>>>(X, T, ghist); break;
        case 1024: k_pass1<32> <<<1024, 256, 0, stream>>>(X, T, ghist); break;
        case 512:  k_pass1<64> <<<512,  256, 0, stream>>>(X, T, ghist); break;
        default:   k_pass1<128><<<256,  256, 0, stream>>>(X, T, ghist); break;
    }
    k_scan <<<B_IMG, 256, 0, stream>>>(ghist, loss, fpart, bpi);
    k_final<<<1, 64, 0, stream>>>(loss, fpart, (float*)d_out);
}

// Round 7
// 54.307 us; speedup vs baseline: 10.6447x; 1.0845x over previous
//
#include <hip/hip_runtime.h>
#include <math.h>

#define KB_   1024                 // z-bins over [-8, 8], Dz = 1/64
#define KPAD  (KB_ + 8)            // copy stride: shifts bank phase by 8
#define B_IMG 32

// ---------------- pass 1: z-binned packed count histogram ------------------
// Per element: z = t? x : -x ; bin = clamp(z*64+512) ; h[bin] += (t<<16)|1.
// Dual LDS copies (lane-parity split) to cut same-address RMW serialization.
template <int ITERS>
__global__ __launch_bounds__(256)
void k_pass1(const float* __restrict__ X, const float* __restrict__ T,
             unsigned* __restrict__ ghist) {
    const int blk = blockIdx.x, tid = threadIdx.x;
    __shared__ __align__(16) unsigned h[2 * KPAD];   // ~8 KB
    for (int i = tid; i < 2 * KPAD; i += 256) h[i] = 0u;
    __syncthreads();

    unsigned* hp = h + (tid & 1) * KPAD;

    const size_t base4 = (size_t)blk * (size_t)ITERS * 256;
    const float4* Xp = (const float4*)X + base4 + tid;
    const float4* Tp = (const float4*)T + base4 + tid;

    auto process = [&](float4 xv, float4 tv) {
#pragma unroll
        for (int j = 0; j < 4; ++j) {
            float x = (&xv.x)[j];
            float t = (&tv.x)[j];
            float s    = __builtin_fmaf(2.f, t, -1.f);           // +1 / -1
            float z    = x * s;                                   // signed logit
            float binf = __builtin_fmaf(z, 64.f, 512.f);
            binf = fminf(fmaxf(binf, 0.f), 1023.f);
            int bin = (int)binf;
            unsigned incr = (unsigned)__builtin_fmaf(t, 65536.f, 1.f); // (t<<16)|1
            atomicAdd(&hp[bin], incr);
        }
    };

    float4 bx[4], bt[4];
#pragma unroll
    for (int r = 0; r < 4; ++r) { bx[r] = Xp[r * 256]; bt[r] = Tp[r * 256]; }
#pragma unroll
    for (int r = 0; r < ITERS; ++r) {
        float4 xv = bx[r & 3], tv = bt[r & 3];
        if (r + 4 < ITERS) {
            bx[r & 3] = Xp[(r + 4) * 256];
            bt[r & 3] = Tp[(r + 4) * 256];
        }
        process(xv, tv);
    }
    __syncthreads();

    unsigned* g = ghist + (size_t)blk * KB_;
    for (int i = tid; i < KB_; i += 256) g[i] = h[i] + h[KPAD + i];
}

// ---------------- per-image: accumulate + suffix scan + analytic dot -------
__global__ __launch_bounds__(256)
void k_scan(const unsigned* __restrict__ ghist, double* __restrict__ loss,
            double* __restrict__ fpart, int bpi) {
    const int img = blockIdx.x, tid = threadIdx.x;
    const unsigned* g = ghist + (size_t)img * (size_t)bpi * KB_;

    uint4 acc = make_uint4(0u, 0u, 0u, 0u);
    for (int j = 0; j < bpi; ++j) {
        uint4 v = *(const uint4*)&g[(size_t)j * KB_ + tid * 4];
        acc.x += v.x; acc.y += v.y; acc.z += v.z; acc.w += v.w;
    }
    unsigned pk[4], ck[4];
    pk[0] = acc.x >> 16; ck[0] = acc.x & 0xffffu;
    pk[1] = acc.y >> 16; ck[1] = acc.y & 0xffffu;
    pk[2] = acc.z >> 16; ck[2] = acc.z & 0xffffu;
    pk[3] = acc.w >> 16; ck[3] = acc.w & 0xffffu;

    unsigned tsum = pk[0] + pk[1] + pk[2] + pk[3];

    __shared__ unsigned sc[2][256];
    sc[0][tid] = tsum;
    __syncthreads();
    int pi = 0;
    for (int off = 1; off < 256; off <<= 1) {
        unsigned val = sc[pi][tid];
        if (tid + off < 256) val += sc[pi][tid + off];
        sc[pi ^ 1][tid] = val;
        __syncthreads();
        pi ^= 1;
    }
    unsigned sufT  = sc[pi][tid] - tsum;   // positives in threads > tid
    unsigned denom = sc[pi][0];            // total positives in image

    double nsum = 0.0, fsum = 0.0;
    unsigned a2 = 0;
#pragma unroll
    for (int i = 3; i >= 0; --i) {
        int b = tid * 4 + i;
        double zc = ((double)b + 0.5 - 512.0) * (1.0 / 64.0);
        double az = fabs(zc);
        double e  = exp(-az);
        double am = (1.0 - e) / (1.0 + e);                         // |margin|
        double om = (zc >= 0.0) ? e / (1.0 + e) : 1.0 / (1.0 + e); // sigmoid(-z)
        double bce = ((zc < 0.0) ? -zc : 0.0) + log1p(e);          // softplus(-z)
        double fk = om * om * bce;
        double Sab = (double)(sufT + a2);                          // pos strictly above
        double c = (double)ck[i], p = (double)pk[i];
        nsum += am * (c * Sab + 0.5 * p * (c + 1.0));
        fsum += fk * c;
        a2 += pk[i];
    }

    for (int o = 32; o > 0; o >>= 1) {
        nsum += __shfl_down(nsum, o, 64);
        fsum += __shfl_down(fsum, o, 64);
    }
    __shared__ double sN[4], sFo[4];
    if ((tid & 63) == 0) { sN[tid >> 6] = nsum; sFo[tid >> 6] = fsum; }
    __syncthreads();
    if (tid == 0) {
        double num = sN[0] + sN[1] + sN[2] + sN[3];
        loss[img]  = (denom == 0u) ? 0.0 : num / fmax((double)denom, 1.0);
        fpart[img] = sFo[0] + sFo[1] + sFo[2] + sFo[3];
    }
}

// ---------------- final combine --------------------------------------------
__global__ __launch_bounds__(64)
void k_final(const double* __restrict__ loss, const double* __restrict__ fpart,
             float* __restrict__ out) {
    const int tid = threadIdx.x;
    double l = (tid < B_IMG) ? loss[tid] : 0.0;
    double f = (tid < B_IMG) ? fpart[tid] : 0.0;
    for (int o = 32; o > 0; o >>= 1) {
        l += __shfl_down(l, o, 64);
        f += __shfl_down(f, o, 64);
    }
    if (tid == 0) {
        double lmean = l / (double)B_IMG;
        double fmean = f / 33554432.0;            // 32 * 2^20 elements
        out[0] = (float)(fabs(0.5 * fmean) + fabs(0.5 * lmean));
    }
}

extern "C" void kernel_launch(void* const* d_in, const int* in_sizes, int n_in,
                              void* d_out, int out_size, void* d_ws, size_t ws_size,
                              hipStream_t stream) {
    const float* X = (const float*)d_in[0];
    const float* T = (const float*)d_in[1];

    int NB = 1024;                                 // 4 blocks/CU, 8 KB LDS each
    for (;;) {
        size_t need = (size_t)NB * KB_ * 4 + 1024;
        if (need <= ws_size || NB <= 256) break;
        NB >>= 1;
    }
    const int bpi = NB / B_IMG;

    unsigned char* ws = (unsigned char*)d_ws;
    unsigned* ghist = (unsigned*)ws;
    double*   loss  = (double*)(ws + (size_t)NB * KB_ * 4);
    double*   fpart = loss + B_IMG;

    switch (NB) {
        case 1024: k_pass1<32> <<<1024, 256, 0, stream>>>(X, T, ghist); break;
        case 512:  k_pass1<64> <<<512,  256, 0, stream>>>(X, T, ghist); break;
        default:   k_pass1<128><<<256,  256, 0, stream>>>(X, T, ghist); break;
    }
    k_scan <<<B_IMG, 256, 0, stream>>>(ghist, loss, fpart, bpi);
    k_final<<<1, 64, 0, stream>>>(loss, fpart, (float*)d_out);
}